// Round 1
// baseline (2334.138 us; speedup 1.0000x reference)
//
#include <hip/hip_runtime.h>
#include <hip/hip_bf16.h>

// MoE top-2 (DeepSpeed-style) forward on MI355X.
// B=2, S_LEN=2048 -> S=4096 tokens, D=2048, E=8, F=5504, capacity=1024.
// Heavy work: per-expert SwiGLU FFN via bf16 MFMA (16x16x32), fp32 accumulate.

#define S_TOT 4096
#define DD 2048
#define EE 8
#define FF 5504
#define CAP 1024
#define OUT_MAIN (S_TOT * DD)   // 8388608 floats, then [l_aux][exp_counts x8]

#define BM 128
#define BN 128
#define BK 32
#define BKP 40   // padded row stride (ushorts) for transposed B tiles in LDS

typedef __bf16 bf16x8 __attribute__((ext_vector_type(8)));
typedef float f32x4 __attribute__((ext_vector_type(4)));

__device__ __forceinline__ unsigned short f2bf(float f) {
    // round-to-nearest-even fp32 -> bf16 (finite inputs)
    unsigned int u = __builtin_bit_cast(unsigned int, f);
    unsigned int lsb = (u >> 16) & 1u;
    u += 0x7fffu + lsb;
    return (unsigned short)(u >> 16);
}

// ---------------- logits = x @ wg  [S,8] ----------------
__global__ void k_logits(const float* __restrict__ x, const float* __restrict__ wg,
                         float* __restrict__ logits) {
    const int s = blockIdx.x;
    const int t = threadIdx.x;  // 256
    const float* xr = x + (size_t)s * DD;
    float part[EE];
#pragma unroll
    for (int e = 0; e < EE; ++e) part[e] = 0.f;
#pragma unroll
    for (int i = 0; i < DD / 256; ++i) {
        int d = t + i * 256;
        float xv = xr[d];
#pragma unroll
        for (int e = 0; e < EE; ++e) part[e] += xv * wg[d * EE + e];
    }
    __shared__ float red[256 * EE];
#pragma unroll
    for (int e = 0; e < EE; ++e) red[t * EE + e] = part[e];
    __syncthreads();
    for (int off = 128; off > 0; off >>= 1) {
        if (t < off) {
#pragma unroll
            for (int e = 0; e < EE; ++e) red[t * EE + e] += red[(t + off) * EE + e];
        }
        __syncthreads();
    }
    if (t < EE) logits[(size_t)s * EE + t] = red[t];
}

// ---------------- top-2 gating, single block, order-preserving scan ----------------
__global__ void k_gating(const float* __restrict__ logits,
                         int* __restrict__ slot1, float* __restrict__ gw1,
                         int* __restrict__ slot2, float* __restrict__ gw2,
                         float* __restrict__ out_extra) {
    const int t = threadIdx.x;  // 256 threads, 16 tokens each (contiguous chunks)
    __shared__ int c1[256][EE];
    __shared__ int c2[256][EE];
    __shared__ float mesh[256][EE];
    __shared__ int tot1[EE];
    __shared__ float me_tot[EE];

    int i1[16], i2[16];
    float g1[16], g2[16];
    int lc1[EE], lc2[EE];
    float lme[EE];
#pragma unroll
    for (int e = 0; e < EE; ++e) { lc1[e] = 0; lc2[e] = 0; lme[e] = 0.f; }

    for (int k = 0; k < 16; ++k) {
        int s = t * 16 + k;
        float lg[EE];
        float m = -1e30f;
#pragma unroll
        for (int e = 0; e < EE; ++e) { lg[e] = logits[(size_t)s * EE + e]; m = fmaxf(m, lg[e]); }
        float ex[EE];
        float sum = 0.f;
#pragma unroll
        for (int e = 0; e < EE; ++e) { ex[e] = expf(lg[e] - m); sum += ex[e]; }
        float inv = 1.f / sum;
        // idx1: first argmax of gates (softmax monotone; ties -> first index)
        float b1v = -1.f; int b1 = 0;
#pragma unroll
        for (int e = 0; e < EE; ++e) {
            float g = ex[e] * inv;
            lme[e] += g;
            if (g > b1v) { b1v = g; b1 = e; }
        }
        // idx2: first argmax of LOGITS with idx1 masked (matches reference exactly)
        float b2l = -3.4e38f; int b2 = 0;
#pragma unroll
        for (int e = 0; e < EE; ++e) {
            if (e != b1 && lg[e] > b2l) { b2l = lg[e]; b2 = e; }
        }
        float b2v = ex[b2] * inv;
        i1[k] = b1; i2[k] = b2; g1[k] = b1v; g2[k] = b2v;
        lc1[b1]++; lc2[b2]++;
    }
#pragma unroll
    for (int e = 0; e < EE; ++e) { c1[t][e] = lc1[e]; c2[t][e] = lc2[e]; mesh[t][e] = lme[e]; }
    __syncthreads();
    // exclusive prefix over thread chunks (token order preserved), per expert
    if (t < 8) {
        int run = 0;
        for (int u = 0; u < 256; ++u) { int v = c1[u][t]; c1[u][t] = run; run += v; }
        tot1[t] = run;  // pre-drop count1 = exp_counts
    } else if (t < 16) {
        int e = t - 8; int run = 0;
        for (int u = 0; u < 256; ++u) { int v = c2[u][e]; c2[u][e] = run; run += v; }
    } else if (t < 24) {
        int e = t - 16; float sm = 0.f;
        for (int u = 0; u < 256; ++u) sm += mesh[u][e];
        me_tot[e] = sm;
    }
    __syncthreads();
    if (t == 0) {
        // l_aux = mean(me*ce)*E^2 = E * sum_e me[e]*ce[e]
        float la = 0.f;
        for (int e = 0; e < EE; ++e)
            la += (me_tot[e] / (float)S_TOT) * ((float)tot1[e] / (float)S_TOT);
        la *= (float)EE;
        out_extra[0] = la;
        for (int e = 0; e < EE; ++e) out_extra[1 + e] = (float)tot1[e];
    }
    int o1[EE], o2[EE];
#pragma unroll
    for (int e = 0; e < EE; ++e) { o1[e] = c1[t][e]; o2[e] = c2[t][e]; }
    for (int k = 0; k < 16; ++k) {
        int s = t * 16 + k;
        int e1 = i1[k]; int p1 = o1[e1]++;
        int e2 = i2[k]; int p2 = o2[e2]++ + tot1[e2];  // loc2 offset by pre-drop count1
        bool k1 = p1 < CAP, k2 = p2 < CAP;
        float a = k1 ? g1[k] : 0.f;
        float b = k2 ? g2[k] : 0.f;
        float den = fmaxf(a + b, 1e-9f);
        slot1[s] = k1 ? (e1 * CAP + p1) : -1;
        slot2[s] = k2 ? (e2 * CAP + p2) : -1;
        gw1[s] = a / den;
        gw2[s] = b / den;
    }
}

// ---------------- zero xe ----------------
__global__ void k_zero(uint4* __restrict__ p, int n16) {
    int i = blockIdx.x * blockDim.x + threadIdx.x;
    if (i < n16) { uint4 z; z.x = 0; z.y = 0; z.z = 0; z.w = 0; p[i] = z; }
}

// ---------------- scatter tokens into xe bf16 [E,C,D] ----------------
__global__ void k_scatter(const float* __restrict__ x, const int* __restrict__ slot1,
                          const int* __restrict__ slot2, unsigned short* __restrict__ xe) {
    const int s = blockIdx.x >> 1;
    const int sl = (blockIdx.x & 1) ? slot2[s] : slot1[s];
    if (sl < 0) return;
    const float* src = x + (size_t)s * DD;
    unsigned short* dst = xe + (size_t)sl * DD;
    const int d = threadIdx.x * 8;  // 256 threads * 8 = 2048
    float4 u0 = *(const float4*)(src + d);
    float4 u1 = *(const float4*)(src + d + 4);
    union { unsigned short u[8]; uint4 v; } pk;
    pk.u[0] = f2bf(u0.x); pk.u[1] = f2bf(u0.y); pk.u[2] = f2bf(u0.z); pk.u[3] = f2bf(u0.w);
    pk.u[4] = f2bf(u1.x); pk.u[5] = f2bf(u1.y); pk.u[6] = f2bf(u1.z); pk.u[7] = f2bf(u1.w);
    *(uint4*)(dst + d) = pk.v;
}

// ---------------- GEMM1 fused SwiGLU: h = silu(xe@w1) * (xe@w3), bf16 out ----------------
__global__ __launch_bounds__(256, 2) void k_gemm1(const unsigned short* __restrict__ xe,
                                                  const float* __restrict__ w1,
                                                  const float* __restrict__ w3,
                                                  unsigned short* __restrict__ h) {
    const int e = blockIdx.z;
    const int cb = blockIdx.y * BM;
    const int fb = blockIdx.x * BN;
    const unsigned short* A = xe + (size_t)e * CAP * DD;
    const float* W1 = w1 + (size_t)e * DD * FF;
    const float* W3 = w3 + (size_t)e * DD * FF;
    __shared__ unsigned short As[BM * BK];
    __shared__ unsigned short B1s[BN * BKP];
    __shared__ unsigned short B3s[BN * BKP];
    const int t = threadIdx.x;
    const int wave = t >> 6, lane = t & 63;
    const int wm = (wave >> 1) * 64, wn = (wave & 1) * 64;
    const int lrow = lane & 15, quad = lane >> 4;
    f32x4 acc1[4][4], acc3[4][4];
#pragma unroll
    for (int i = 0; i < 4; ++i)
#pragma unroll
        for (int j = 0; j < 4; ++j) {
            acc1[i][j] = (f32x4){0.f, 0.f, 0.f, 0.f};
            acc3[i][j] = (f32x4){0.f, 0.f, 0.f, 0.f};
        }
    const int kk = t >> 3;          // 0..31 (K row within tile)
    const int ffo = (t & 7) * 16;   // 0..112 (N col segment)
    for (int k0 = 0; k0 < DD; k0 += BK) {
        // stage A (bf16, K-major): 128x32
#pragma unroll
        for (int i = 0; i < 2; ++i) {
            int idx = t + i * 256;
            int r = idx >> 2, seg = idx & 3;
            *(uint4*)&As[r * BK + seg * 8] =
                *(const uint4*)&A[(size_t)(cb + r) * DD + k0 + seg * 8];
        }
        // stage B1/B3: read fp32 rows coalesced, convert to bf16, write transposed
        {
            const float* p1 = &W1[(size_t)(k0 + kk) * FF + fb + ffo];
            const float* p3 = &W3[(size_t)(k0 + kk) * FF + fb + ffo];
            float4 va[4], vc[4];
#pragma unroll
            for (int q = 0; q < 4; ++q) { va[q] = *(const float4*)(p1 + q * 4); }
#pragma unroll
            for (int q = 0; q < 4; ++q) { vc[q] = *(const float4*)(p3 + q * 4); }
            unsigned short* q1 = &B1s[ffo * BKP + kk];
            unsigned short* q3 = &B3s[ffo * BKP + kk];
#pragma unroll
            for (int q = 0; q < 4; ++q) {
                q1[(q * 4 + 0) * BKP] = f2bf(va[q].x);
                q1[(q * 4 + 1) * BKP] = f2bf(va[q].y);
                q1[(q * 4 + 2) * BKP] = f2bf(va[q].z);
                q1[(q * 4 + 3) * BKP] = f2bf(va[q].w);
                q3[(q * 4 + 0) * BKP] = f2bf(vc[q].x);
                q3[(q * 4 + 1) * BKP] = f2bf(vc[q].y);
                q3[(q * 4 + 2) * BKP] = f2bf(vc[q].z);
                q3[(q * 4 + 3) * BKP] = f2bf(vc[q].w);
            }
        }
        __syncthreads();
        bf16x8 af[4], bf1[4], bf3[4];
#pragma unroll
        for (int i = 0; i < 4; ++i)
            af[i] = *(const bf16x8*)&As[(wm + i * 16 + lrow) * BK + quad * 8];
#pragma unroll
        for (int j = 0; j < 4; ++j) {
            bf1[j] = *(const bf16x8*)&B1s[(wn + j * 16 + lrow) * BKP + quad * 8];
            bf3[j] = *(const bf16x8*)&B3s[(wn + j * 16 + lrow) * BKP + quad * 8];
        }
#pragma unroll
        for (int i = 0; i < 4; ++i)
#pragma unroll
            for (int j = 0; j < 4; ++j) {
                acc1[i][j] = __builtin_amdgcn_mfma_f32_16x16x32_bf16(af[i], bf1[j], acc1[i][j], 0, 0, 0);
                acc3[i][j] = __builtin_amdgcn_mfma_f32_16x16x32_bf16(af[i], bf3[j], acc3[i][j], 0, 0, 0);
            }
        __syncthreads();
    }
    unsigned short* H = h + (size_t)e * CAP * FF;
#pragma unroll
    for (int i = 0; i < 4; ++i)
#pragma unroll
        for (int j = 0; j < 4; ++j)
#pragma unroll
            for (int r = 0; r < 4; ++r) {
                float v1 = acc1[i][j][r], v3 = acc3[i][j][r];
                float hv = (v1 / (1.f + __expf(-v1))) * v3;  // silu(v1)*v3
                int row = cb + wm + i * 16 + quad * 4 + r;   // C/D: row=quad*4+reg
                int col = fb + wn + j * 16 + lrow;           //      col=lane&15
                H[(size_t)row * FF + col] = f2bf(hv);
            }
}

// ---------------- GEMM2: eo = h @ w2, fp32 out ----------------
__global__ __launch_bounds__(256, 2) void k_gemm2(const unsigned short* __restrict__ h,
                                                  const float* __restrict__ w2,
                                                  float* __restrict__ eo) {
    const int e = blockIdx.z;
    const int cb = blockIdx.y * BM;
    const int db = blockIdx.x * BN;
    const unsigned short* A = h + (size_t)e * CAP * FF;
    const float* W = w2 + (size_t)e * FF * DD;
    __shared__ unsigned short As[BM * BK];
    __shared__ unsigned short Bs[BN * BKP];
    const int t = threadIdx.x;
    const int wave = t >> 6, lane = t & 63;
    const int wm = (wave >> 1) * 64, wn = (wave & 1) * 64;
    const int lrow = lane & 15, quad = lane >> 4;
    f32x4 acc[4][4];
#pragma unroll
    for (int i = 0; i < 4; ++i)
#pragma unroll
        for (int j = 0; j < 4; ++j) acc[i][j] = (f32x4){0.f, 0.f, 0.f, 0.f};
    const int kk = t >> 3;
    const int ffo = (t & 7) * 16;
    for (int k0 = 0; k0 < FF; k0 += BK) {  // 172 iters
#pragma unroll
        for (int i = 0; i < 2; ++i) {
            int idx = t + i * 256;
            int r = idx >> 2, seg = idx & 3;
            *(uint4*)&As[r * BK + seg * 8] =
                *(const uint4*)&A[(size_t)(cb + r) * FF + k0 + seg * 8];
        }
        {
            const float* p = &W[(size_t)(k0 + kk) * DD + db + ffo];
            float4 v[4];
#pragma unroll
            for (int q = 0; q < 4; ++q) v[q] = *(const float4*)(p + q * 4);
            unsigned short* qb = &Bs[ffo * BKP + kk];
#pragma unroll
            for (int q = 0; q < 4; ++q) {
                qb[(q * 4 + 0) * BKP] = f2bf(v[q].x);
                qb[(q * 4 + 1) * BKP] = f2bf(v[q].y);
                qb[(q * 4 + 2) * BKP] = f2bf(v[q].z);
                qb[(q * 4 + 3) * BKP] = f2bf(v[q].w);
            }
        }
        __syncthreads();
        bf16x8 af[4], bf[4];
#pragma unroll
        for (int i = 0; i < 4; ++i)
            af[i] = *(const bf16x8*)&As[(wm + i * 16 + lrow) * BK + quad * 8];
#pragma unroll
        for (int j = 0; j < 4; ++j)
            bf[j] = *(const bf16x8*)&Bs[(wn + j * 16 + lrow) * BKP + quad * 8];
#pragma unroll
        for (int i = 0; i < 4; ++i)
#pragma unroll
            for (int j = 0; j < 4; ++j)
                acc[i][j] = __builtin_amdgcn_mfma_f32_16x16x32_bf16(af[i], bf[j], acc[i][j], 0, 0, 0);
        __syncthreads();
    }
    float* O = eo + (size_t)e * CAP * DD;
#pragma unroll
    for (int i = 0; i < 4; ++i)
#pragma unroll
        for (int j = 0; j < 4; ++j)
#pragma unroll
            for (int r = 0; r < 4; ++r) {
                int row = cb + wm + i * 16 + quad * 4 + r;
                int col = db + wn + j * 16 + lrow;
                O[(size_t)row * DD + col] = acc[i][j][r];
            }
}

// ---------------- combine: out[s] = g1*eo[slot1] + g2*eo[slot2] ----------------
__global__ void k_combine(const float* __restrict__ eo,
                          const int* __restrict__ slot1, const float* __restrict__ gw1,
                          const int* __restrict__ slot2, const float* __restrict__ gw2,
                          float* __restrict__ out) {
    const int s = blockIdx.x, t = threadIdx.x;
    const int sl1 = slot1[s], sl2 = slot2[s];
    const float a = gw1[s], b = gw2[s];
    const int d = t * 8;
    float r[8];
#pragma unroll
    for (int j = 0; j < 8; ++j) r[j] = 0.f;
    if (sl1 >= 0) {
        const float* p = eo + (size_t)sl1 * DD + d;
        float4 u0 = *(const float4*)p, u1 = *(const float4*)(p + 4);
        r[0] += a * u0.x; r[1] += a * u0.y; r[2] += a * u0.z; r[3] += a * u0.w;
        r[4] += a * u1.x; r[5] += a * u1.y; r[6] += a * u1.z; r[7] += a * u1.w;
    }
    if (sl2 >= 0) {
        const float* p = eo + (size_t)sl2 * DD + d;
        float4 u0 = *(const float4*)p, u1 = *(const float4*)(p + 4);
        r[0] += b * u0.x; r[1] += b * u0.y; r[2] += b * u0.z; r[3] += b * u0.w;
        r[4] += b * u1.x; r[5] += b * u1.y; r[6] += b * u1.z; r[7] += b * u1.w;
    }
    float* q = out + (size_t)s * DD + d;
    float4 w0, w1v;
    w0.x = r[0]; w0.y = r[1]; w0.z = r[2]; w0.w = r[3];
    w1v.x = r[4]; w1v.y = r[5]; w1v.z = r[6]; w1v.w = r[7];
    *(float4*)q = w0;
    *(float4*)(q + 4) = w1v;
}

extern "C" void kernel_launch(void* const* d_in, const int* in_sizes, int n_in,
                              void* d_out, int out_size, void* d_ws, size_t ws_size,
                              hipStream_t stream) {
    const float* x  = (const float*)d_in[0];  // [2,2048,2048]
    const float* wg = (const float*)d_in[1];  // [2048,8]
    const float* w1 = (const float*)d_in[2];  // [8,2048,5504]
    const float* w3 = (const float*)d_in[3];  // [8,2048,5504]
    const float* w2 = (const float*)d_in[4];  // [8,5504,2048]
    float* out = (float*)d_out;

    char* ws = (char*)d_ws;
    size_t off = 0;
    float* logits = (float*)(ws + off); off += (size_t)S_TOT * EE * 4;
    int* slot1    = (int*)(ws + off);   off += (size_t)S_TOT * 4;
    float* gw1    = (float*)(ws + off); off += (size_t)S_TOT * 4;
    int* slot2    = (int*)(ws + off);   off += (size_t)S_TOT * 4;
    float* gw2    = (float*)(ws + off); off += (size_t)S_TOT * 4;
    unsigned short* xe   = (unsigned short*)(ws + off); off += (size_t)EE * CAP * DD * 2;
    unsigned short* hbuf = (unsigned short*)(ws + off); off += (size_t)EE * CAP * FF * 2;
    float* eo     = (float*)(ws + off); off += (size_t)EE * CAP * DD * 4;
    // total ~191 MB

    k_logits<<<S_TOT, 256, 0, stream>>>(x, wg, logits);
    k_gating<<<1, 256, 0, stream>>>(logits, slot1, gw1, slot2, gw2, out + OUT_MAIN);
    int n16 = (int)((size_t)EE * CAP * DD * 2 / 16);
    k_zero<<<(n16 + 255) / 256, 256, 0, stream>>>((uint4*)xe, n16);
    k_scatter<<<S_TOT * 2, 256, 0, stream>>>(x, slot1, slot2, xe);
    k_gemm1<<<dim3(FF / BN, CAP / BM, EE), 256, 0, stream>>>(xe, w1, w3, hbuf);
    k_gemm2<<<dim3(DD / BN, CAP / BM, EE), 256, 0, stream>>>(hbuf, w2, eo);
    k_combine<<<S_TOT, 256, 0, stream>>>(eo, slot1, gw1, slot2, gw2, out);
}